// Round 8
// baseline (742.680 us; speedup 1.0000x reference)
//
#include <hip/hip_runtime.h>
#include <hip/hip_bf16.h>

#define FDIM 128
#define HDIM 32
#define BN_EPS 1e-5f
#define BK 256         // destination nodes per bucket
#define NBITS 8        // log2(BK)
#define CHUNK_H 4096   // edges per hist block
#define CHUNK_P 8192   // edges per partition block
#define BMAX 512       // max buckets (N <= 131072)

// ---------- per-bucket histogram (LDS) ----------
__global__ void k_hist2(const int* __restrict__ col, int* __restrict__ bcounts, int E, int B) {
    __shared__ int h[BMAX];
    for (int i = threadIdx.x; i < B; i += 256) h[i] = 0;
    __syncthreads();
    int base = blockIdx.x * CHUNK_H;
    int end = min(base + CHUNK_H, E);
    for (int e = base + threadIdx.x; e < end; e += 256)
        atomicAdd(&h[col[e] >> NBITS], 1);
    __syncthreads();
    for (int i = threadIdx.x; i < B; i += 256)
        if (h[i]) atomicAdd(&bcounts[i], h[i]);
}

// ---------- single-block exclusive scan of bucket counts ----------
__global__ void k_bscan(const int* __restrict__ bcounts, int* __restrict__ boff,
                        int* __restrict__ bcur, int* __restrict__ noff, int B, int E, int N) {
    __shared__ int tsum[256];
    __shared__ int wtot[4];
    const int t = threadIdx.x;
    const int per = (B + 255) / 256;
    const int b0 = t * per;
    int s = 0;
    for (int k = 0; k < per; ++k) { int i = b0 + k; if (i < B) s += bcounts[i]; }
    tsum[t] = s;
    __syncthreads();
    int lane = t & 63, w = t >> 6;
    int v = tsum[t];
    int inc = v;
    for (int off = 1; off < 64; off <<= 1) {
        int u = __shfl_up(inc, off);
        if (lane >= off) inc += u;
    }
    if (lane == 63) wtot[w] = inc;
    __syncthreads();
    int pre = 0;
    for (int k = 0; k < w; ++k) pre += wtot[k];
    int acc = pre + inc - v;  // exclusive prefix
    for (int k = 0; k < per; ++k) {
        int i = b0 + k;
        if (i < B) { boff[i] = acc; bcur[i] = acc; acc += bcounts[i]; }
    }
    if (t == 0) { boff[B] = E; noff[N] = E; }
}

// ---------- partition with LDS staging: pairs[] grouped by dst bucket, coalesced writes ----------
__global__ __launch_bounds__(256) void k_partition(const int* __restrict__ row,
                                                   const int* __restrict__ col,
                                                   int* __restrict__ bcur,
                                                   unsigned* __restrict__ pairs,
                                                   int E, int B) {
    __shared__ int h[BMAX];          // counts -> local cursors
    __shared__ int lbase[BMAX + 1];  // local exclusive scan
    __shared__ int delta[BMAX];      // global_base - local_base
    __shared__ unsigned pk[CHUNK_P]; // bucket-sorted packed pairs
    const int t = threadIdx.x;
    const int base = blockIdx.x * CHUNK_P;
    const int end = min(base + CHUNK_P, E);

    for (int i = t; i < B; i += 256) h[i] = 0;
    __syncthreads();
    // phase 1: local histogram
    for (int e = base + t; e < end; e += 256)
        atomicAdd(&h[col[e] >> NBITS], 1);
    __syncthreads();
    // phase 2: exclusive scan of h -> lbase (wave 0)
    if (t < 64) {
        int carry = 0;
        for (int bb = 0; bb < B; bb += 64) {
            int idx = bb + t;
            int v = (idx < B) ? h[idx] : 0;
            int inc = v;
            for (int off = 1; off < 64; off <<= 1) {
                int u = __shfl_up(inc, off);
                if (t >= off) inc += u;
            }
            if (idx < B) lbase[idx] = carry + inc - v;
            carry += __shfl(inc, 63);
        }
        if (t == 0) lbase[B] = carry;
    }
    __syncthreads();
    // phase 3: reserve global ranges
    for (int b = t; b < B; b += 256) {
        int c = h[b];
        if (c) {
            int g = atomicAdd(&bcur[b], c);
            delta[b] = g - lbase[b];
        }
    }
    __syncthreads();
    // phase 4: counting-sort into LDS (h becomes cursor)
    for (int b = t; b < B; b += 256) h[b] = lbase[b];
    __syncthreads();
    for (int e = base + t; e < end; e += 256) {
        int c = col[e], r = row[e];
        int lpos = atomicAdd(&h[c >> NBITS], 1);
        pk[lpos] = ((unsigned)r << NBITS) | (unsigned)(c & (BK - 1));
    }
    __syncthreads();
    // phase 5: coalesced write-out (binary search bucket for each position)
    const int tot = lbase[B];
    for (int i = t; i < tot; i += 256) {
        int lo = 0, hi = B - 1;
        while (lo < hi) {
            int mid = (lo + hi + 1) >> 1;
            if (lbase[mid] <= i) lo = mid; else hi = mid - 1;
        }
        pairs[delta[lo] + i] = pk[i];
    }
}

// ---------- per-bucket counting sort -> exact CSR (srcs, noff) + dinv ----------
__global__ __launch_bounds__(1024) void k_sort(const unsigned* __restrict__ pairs,
                                               const int* __restrict__ boff,
                                               int* __restrict__ srcs, int* __restrict__ noff,
                                               float* __restrict__ dinv, int N) {
    __shared__ int cnt[BK];
    __shared__ int cur[BK];
    const int bb = blockIdx.x;
    const int t = threadIdx.x;
    if (t < BK) cnt[t] = 0;
    __syncthreads();
    const int beg = boff[bb], end = boff[bb + 1];
    for (int i = beg + t; i < end; i += 1024)
        atomicAdd(&cnt[pairs[i] & (BK - 1)], 1);
    __syncthreads();
    if (t < 64) {  // wave 0: exclusive scan of BK counts
        int carry = 0;
        for (int base = 0; base < BK; base += 64) {
            int v = cnt[base + t];
            int inc = v;
            for (int off = 1; off < 64; off <<= 1) {
                int u = __shfl_up(inc, off);
                if (t >= off) inc += u;
            }
            cur[base + t] = beg + carry + inc - v;
            carry += __shfl(inc, 63);
        }
    }
    __syncthreads();
    if (t < BK) {
        int n = bb * BK + t;
        if (n < N) {
            noff[n] = cur[t];
            dinv[n] = rsqrtf((float)(cnt[t] + 1));  // +1 self-loop
        }
    }
    __syncthreads();
    for (int i = beg + t; i < end; i += 1024) {
        unsigned p = pairs[i];
        int pos = atomicAdd(&cur[p & (BK - 1)], 1);
        srcs[pos] = (int)(p >> NBITS);
    }
}

// ---------- GEMM: Y split-layout bf16; Y_lo[n][16] cols 0-15, Y_hi at +n*16.
// optional fused BN+ReLU on X ----------
template <int K, bool APPLY_BN>
__global__ void k_gemm(const float* __restrict__ X, const float* __restrict__ W,
                       const float* __restrict__ dinv, __hip_bfloat16* __restrict__ Y, int n,
                       const float* __restrict__ stats, const float* __restrict__ gamma,
                       const float* __restrict__ beta, float invN) {
    __shared__ __align__(16) float Ws[K * HDIM];
    __shared__ __align__(16) float Xs[8 * K];
    __shared__ float bnsc[K], bnsh[K];
    const int tid = threadIdx.x;
    const int row0 = blockIdx.x * 8;

    if (APPLY_BN) {
        if (tid < K) {
            float mean = stats[tid] * invN;
            float var = stats[K + tid] * invN - mean * mean;
            float sc = gamma[tid] * rsqrtf(var + BN_EPS);
            bnsc[tid] = sc;
            bnsh[tid] = beta[tid] - mean * sc;
        }
        __syncthreads();
    }
    for (int i = tid * 4; i < K * HDIM; i += 1024) {
        *(float4*)&Ws[i] = *(const float4*)&W[i];
    }
    for (int i = tid * 4; i < 8 * K; i += 1024) {
        int r = i / K, k = i % K;
        int gr = row0 + r;
        float4 v = make_float4(0.f, 0.f, 0.f, 0.f);
        if (gr < n) v = *(const float4*)&X[(size_t)gr * K + k];
        if (APPLY_BN) {
            v.x = fmaxf(v.x * bnsc[k]     + bnsh[k],     0.f);
            v.y = fmaxf(v.y * bnsc[k + 1] + bnsh[k + 1], 0.f);
            v.z = fmaxf(v.z * bnsc[k + 2] + bnsh[k + 2], 0.f);
            v.w = fmaxf(v.w * bnsc[k + 3] + bnsh[k + 3], 0.f);
        }
        *(float4*)&Xs[i] = v;
    }
    __syncthreads();
    const int r = tid >> 5, c = tid & 31;
    const int grow = row0 + r;
    if (grow < n) {
        float acc = 0.f;
#pragma unroll
        for (int k = 0; k < K; ++k) acc += Xs[r * K + k] * Ws[k * HDIM + c];
        // split write: cols 0-15 -> Y, cols 16-31 -> Y + n*16
        __hip_bfloat16* dst = Y + ((c < 16) ? (size_t)0 : (size_t)n * 16);
        dst[(size_t)grow * 16 + (c & 15)] = __float2bfloat16(dinv[grow] * acc);
    }
}

// ---------- gather-aggregate over ONE feature split (16 cols):
// agg[n][c0+j] = dinv[n]*(hp[n][j]+sum hp[src][j])+b[c0+j] ; fused BN-stats.
// quarter-wave (16 lanes) per row; 4 edges in flight per instruction.
__global__ __launch_bounds__(256) void k_aggregate_split(const __hip_bfloat16* __restrict__ hp,
                                                         const float* __restrict__ dinv,
                                                         const int* __restrict__ offsets,
                                                         const int* __restrict__ srcs,
                                                         const float* __restrict__ bias,
                                                         float* __restrict__ agg,
                                                         float* __restrict__ stats,
                                                         int N, int c0) {
    const int tid = threadIdx.x;
    const int lane = tid & 63;
    const int j = lane & 15;
    const int q = lane >> 4;  // quarter 0..3
    const int wid = (blockIdx.x * 256 + tid) >> 6;
    const int nw = (gridDim.x * 256) >> 6;
    const float bj = bias[c0 + j];
    float s = 0.f, s2 = 0.f;

    for (int n = wid; n < N; n += nw) {
        int beg = offsets[n], end = offsets[n + 1];
        float acc = (q == 0) ? __bfloat162float(hp[(size_t)n * 16 + j]) : 0.f;  // self-loop once
        int e = beg + q;
        for (; e + 60 < end; e += 64) {  // 16 outstanding gathers per quarter
            int rr[16];
            float vv[16];
#pragma unroll
            for (int k = 0; k < 16; ++k) rr[k] = srcs[e + 4 * k];
#pragma unroll
            for (int k = 0; k < 16; ++k) vv[k] = __bfloat162float(hp[(size_t)rr[k] * 16 + j]);
#pragma unroll
            for (int k = 0; k < 16; ++k) acc += vv[k];
        }
        for (; e + 12 < end; e += 16) {
            int r0 = srcs[e], r1 = srcs[e + 4], r2 = srcs[e + 8], r3 = srcs[e + 12];
            float v0 = __bfloat162float(hp[(size_t)r0 * 16 + j]);
            float v1 = __bfloat162float(hp[(size_t)r1 * 16 + j]);
            float v2 = __bfloat162float(hp[(size_t)r2 * 16 + j]);
            float v3 = __bfloat162float(hp[(size_t)r3 * 16 + j]);
            acc += (v0 + v1) + (v2 + v3);
        }
        for (; e < end; e += 4) acc += __bfloat162float(hp[(size_t)srcs[e] * 16 + j]);
        acc += __shfl_xor(acc, 16);  // combine quarters
        acc += __shfl_xor(acc, 32);
        float out = dinv[n] * acc + bj;
        if (q == 0) agg[(size_t)n * HDIM + c0 + j] = out;
        s += out;                     // 4 copies -> scale 0.25 at flush
        s2 += out * out;
    }

    __shared__ float ls[4][64], ls2[4][64];
    int w = tid >> 6;
    ls[w][lane] = s;
    ls2[w][lane] = s2;
    __syncthreads();
    if (tid < 16) {
        float t = 0.f;
#pragma unroll
        for (int k = 0; k < 4; ++k)
            t += (ls[k][tid] + ls[k][tid + 16]) + (ls[k][tid + 32] + ls[k][tid + 48]);
        atomicAdd(&stats[c0 + tid], 0.25f * t);
    } else if (tid < 32) {
        int jj = tid - 16;
        float t = 0.f;
#pragma unroll
        for (int k = 0; k < 4; ++k)
            t += (ls2[k][jj] + ls2[k][jj + 16]) + (ls2[k][jj + 32] + ls2[k][jj + 48]);
        atomicAdd(&stats[32 + c0 + jj], 0.25f * t);
    }
}

// ---------- final batchnorm apply (layer 2, no relu), float4 ----------
__global__ void k_bnapply(const float* __restrict__ a, const float* __restrict__ stats,
                          const float* __restrict__ gamma, const float* __restrict__ beta,
                          float* __restrict__ out, int n, float invN) {
    int i = (blockIdx.x * 256 + threadIdx.x) * 4;
    if (i < n * HDIM) {
        int j = i & 31;
        float4 v = *(const float4*)&a[i];
        float r[4];
        float* vp = &v.x;
#pragma unroll
        for (int k = 0; k < 4; ++k) {
            float mean = stats[j + k] * invN;
            float var = stats[HDIM + j + k] * invN - mean * mean;
            float g = gamma[j + k] * rsqrtf(var + BN_EPS);
            r[k] = (vp[k] - mean) * g + beta[j + k];
        }
        *(float4*)&out[i] = make_float4(r[0], r[1], r[2], r[3]);
    }
}

extern "C" void kernel_launch(void* const* d_in, const int* in_sizes, int n_in,
                              void* d_out, int out_size, void* d_ws, size_t ws_size,
                              hipStream_t stream) {
    const float* x   = (const float*)d_in[0];
    const int*   ei  = (const int*)d_in[1];
    const float* W1  = (const float*)d_in[2];
    const float* b1  = (const float*)d_in[3];
    const float* g1  = (const float*)d_in[4];
    const float* be1 = (const float*)d_in[5];
    const float* W2  = (const float*)d_in[6];
    const float* b2  = (const float*)d_in[7];
    const float* g2  = (const float*)d_in[8];
    const float* be2 = (const float*)d_in[9];

    const int N = in_sizes[0] / FDIM;
    const int E = in_sizes[1] / 2;
    const int* row = ei;      // source
    const int* col = ei + E;  // target
    const int B = (N + BK - 1) / BK;   // buckets (391 for N=100k, fits BMAX)

    char* p = (char*)d_ws;
    auto alloc = [&](size_t bytes) { char* r = p; p += (bytes + 255) & ~(size_t)255; return r; };
    float*          dinv    = (float*)alloc((size_t)N * 4);
    int*            bcounts = (int*)alloc((size_t)B * 4);
    int*            boff    = (int*)alloc((size_t)(B + 1) * 4);
    int*            bcur    = (int*)alloc((size_t)B * 4);
    int*            noff    = (int*)alloc((size_t)(N + 1) * 4);
    unsigned*       pairs   = (unsigned*)alloc((size_t)E * 4);
    int*            srcs    = (int*)alloc((size_t)E * 4);
    __hip_bfloat16* B1      = (__hip_bfloat16*)alloc((size_t)N * HDIM * 2);  // hp split: lo | hi
    float*          B2      = (float*)alloc((size_t)N * HDIM * 4);           // agg (fp32)
    float*          stats   = (float*)alloc(512);  // layer1 [0,64), layer2 [64,128)

    __hip_bfloat16* hpLo = B1;                      // [N][16] cols 0-15
    __hip_bfloat16* hpHi = B1 + (size_t)N * 16;     // [N][16] cols 16-31

    const float invN = 1.0f / (float)N;
    const int EBH = (E + CHUNK_H - 1) / CHUNK_H;
    const int EBP = (E + CHUNK_P - 1) / CHUNK_P;

    (void)hipMemsetAsync(bcounts, 0, (size_t)B * 4, stream);
    (void)hipMemsetAsync(stats, 0, 512, stream);

    // bucketed edge partition + per-bucket counting sort -> exact CSR (shared by both layers)
    k_hist2<<<EBH, 256, 0, stream>>>(col, bcounts, E, B);
    k_bscan<<<1, 256, 0, stream>>>(bcounts, boff, bcur, noff, B, E, N);
    k_partition<<<EBP, 256, 0, stream>>>(row, col, bcur, pairs, E, B);
    k_sort<<<B, 1024, 0, stream>>>(pairs, boff, srcs, noff, dinv, N);

    // layer 1: two sequential feature-split aggregate passes (each split fits per-XCD L2)
    k_gemm<FDIM, false><<<(N + 7) / 8, 256, 0, stream>>>(x, W1, dinv, B1, N,
                                                         nullptr, nullptr, nullptr, 0.f);
    k_aggregate_split<<<2048, 256, 0, stream>>>(hpLo, dinv, noff, srcs, b1, B2, stats, N, 0);
    k_aggregate_split<<<2048, 256, 0, stream>>>(hpHi, dinv, noff, srcs, b1, B2, stats, N, 16);

    // layer 2 (BN1+ReLU fused into gemm2's X load)
    k_gemm<HDIM, true><<<(N + 7) / 8, 256, 0, stream>>>(B2, W2, dinv, B1, N,
                                                        stats, g1, be1, invN);
    k_aggregate_split<<<2048, 256, 0, stream>>>(hpLo, dinv, noff, srcs, b2, B2,
                                                stats + 2 * HDIM, N, 0);
    k_aggregate_split<<<2048, 256, 0, stream>>>(hpHi, dinv, noff, srcs, b2, B2,
                                                stats + 2 * HDIM, N, 16);
    k_bnapply<<<(N * HDIM / 4 + 255) / 256, 256, 0, stream>>>(B2, stats + 2 * HDIM, g2, be2,
                                                              (float*)d_out, N, invN);
}

// Round 9
// 620.874 us; speedup vs baseline: 1.1962x; 1.1962x over previous
//
#include <hip/hip_runtime.h>
#include <hip/hip_bf16.h>

#define FDIM 128
#define HDIM 32
#define BN_EPS 1e-5f
#define BK 256         // destination nodes per bucket
#define NBITS 8        // log2(BK)
#define CHUNK_H 4096   // edges per hist block
#define CHUNK_P 8192   // edges per partition block
#define BMAX 512       // max buckets (N <= 131072)

// ---------- per-bucket histogram (LDS) ----------
__global__ void k_hist2(const int* __restrict__ col, int* __restrict__ bcounts, int E, int B) {
    __shared__ int h[BMAX];
    for (int i = threadIdx.x; i < B; i += 256) h[i] = 0;
    __syncthreads();
    int base = blockIdx.x * CHUNK_H;
    int end = min(base + CHUNK_H, E);
    for (int e = base + threadIdx.x; e < end; e += 256)
        atomicAdd(&h[col[e] >> NBITS], 1);
    __syncthreads();
    for (int i = threadIdx.x; i < B; i += 256)
        if (h[i]) atomicAdd(&bcounts[i], h[i]);
}

// ---------- single-block exclusive scan of bucket counts ----------
__global__ void k_bscan(const int* __restrict__ bcounts, int* __restrict__ boff,
                        int* __restrict__ bcur, int* __restrict__ noff, int B, int E, int N) {
    __shared__ int tsum[256];
    __shared__ int wtot[4];
    const int t = threadIdx.x;
    const int per = (B + 255) / 256;
    const int b0 = t * per;
    int s = 0;
    for (int k = 0; k < per; ++k) { int i = b0 + k; if (i < B) s += bcounts[i]; }
    tsum[t] = s;
    __syncthreads();
    int lane = t & 63, w = t >> 6;
    int v = tsum[t];
    int inc = v;
    for (int off = 1; off < 64; off <<= 1) {
        int u = __shfl_up(inc, off);
        if (lane >= off) inc += u;
    }
    if (lane == 63) wtot[w] = inc;
    __syncthreads();
    int pre = 0;
    for (int k = 0; k < w; ++k) pre += wtot[k];
    int acc = pre + inc - v;  // exclusive prefix
    for (int k = 0; k < per; ++k) {
        int i = b0 + k;
        if (i < B) { boff[i] = acc; bcur[i] = acc; acc += bcounts[i]; }
    }
    if (t == 0) { boff[B] = E; noff[N] = E; }
}

// ---------- partition with LDS staging: pairs[] grouped by dst bucket, coalesced writes ----------
__global__ __launch_bounds__(256) void k_partition(const int* __restrict__ row,
                                                   const int* __restrict__ col,
                                                   int* __restrict__ bcur,
                                                   unsigned* __restrict__ pairs,
                                                   int E, int B) {
    __shared__ int h[BMAX];          // counts -> local cursors
    __shared__ int lbase[BMAX + 1];  // local exclusive scan
    __shared__ int delta[BMAX];      // global_base - local_base
    __shared__ unsigned pk[CHUNK_P]; // bucket-sorted packed pairs
    const int t = threadIdx.x;
    const int base = blockIdx.x * CHUNK_P;
    const int end = min(base + CHUNK_P, E);

    for (int i = t; i < B; i += 256) h[i] = 0;
    __syncthreads();
    for (int e = base + t; e < end; e += 256)
        atomicAdd(&h[col[e] >> NBITS], 1);
    __syncthreads();
    if (t < 64) {
        int carry = 0;
        for (int bb = 0; bb < B; bb += 64) {
            int idx = bb + t;
            int v = (idx < B) ? h[idx] : 0;
            int inc = v;
            for (int off = 1; off < 64; off <<= 1) {
                int u = __shfl_up(inc, off);
                if (t >= off) inc += u;
            }
            if (idx < B) lbase[idx] = carry + inc - v;
            carry += __shfl(inc, 63);
        }
        if (t == 0) lbase[B] = carry;
    }
    __syncthreads();
    for (int b = t; b < B; b += 256) {
        int c = h[b];
        if (c) {
            int g = atomicAdd(&bcur[b], c);
            delta[b] = g - lbase[b];
        }
    }
    __syncthreads();
    for (int b = t; b < B; b += 256) h[b] = lbase[b];
    __syncthreads();
    for (int e = base + t; e < end; e += 256) {
        int c = col[e], r = row[e];
        int lpos = atomicAdd(&h[c >> NBITS], 1);
        pk[lpos] = ((unsigned)r << NBITS) | (unsigned)(c & (BK - 1));
    }
    __syncthreads();
    const int tot = lbase[B];
    for (int i = t; i < tot; i += 256) {
        int lo = 0, hi = B - 1;
        while (lo < hi) {
            int mid = (lo + hi + 1) >> 1;
            if (lbase[mid] <= i) lo = mid; else hi = mid - 1;
        }
        pairs[delta[lo] + i] = pk[i];
    }
}

// ---------- per-bucket counting sort -> exact CSR (srcs, noff) + dinv ----------
__global__ __launch_bounds__(1024) void k_sort(const unsigned* __restrict__ pairs,
                                               const int* __restrict__ boff,
                                               int* __restrict__ srcs, int* __restrict__ noff,
                                               float* __restrict__ dinv, int N) {
    __shared__ int cnt[BK];
    __shared__ int cur[BK];
    const int bb = blockIdx.x;
    const int t = threadIdx.x;
    if (t < BK) cnt[t] = 0;
    __syncthreads();
    const int beg = boff[bb], end = boff[bb + 1];
    for (int i = beg + t; i < end; i += 1024)
        atomicAdd(&cnt[pairs[i] & (BK - 1)], 1);
    __syncthreads();
    if (t < 64) {
        int carry = 0;
        for (int base = 0; base < BK; base += 64) {
            int v = cnt[base + t];
            int inc = v;
            for (int off = 1; off < 64; off <<= 1) {
                int u = __shfl_up(inc, off);
                if (t >= off) inc += u;
            }
            cur[base + t] = beg + carry + inc - v;
            carry += __shfl(inc, 63);
        }
    }
    __syncthreads();
    if (t < BK) {
        int n = bb * BK + t;
        if (n < N) {
            noff[n] = cur[t];
            dinv[n] = rsqrtf((float)(cnt[t] + 1));  // +1 self-loop
        }
    }
    __syncthreads();
    for (int i = beg + t; i < end; i += 1024) {
        unsigned p = pairs[i];
        int pos = atomicAdd(&cur[p & (BK - 1)], 1);
        srcs[pos] = (int)(p >> NBITS);
    }
}

// ---------- GEMM: Y[n,32] = bf16(dinv[n]*(X[n,K]@W[K,32])); optional fused BN+ReLU on X ----------
template <int K, bool APPLY_BN>
__global__ void k_gemm(const float* __restrict__ X, const float* __restrict__ W,
                       const float* __restrict__ dinv, __hip_bfloat16* __restrict__ Y, int n,
                       const float* __restrict__ stats, const float* __restrict__ gamma,
                       const float* __restrict__ beta, float invN) {
    __shared__ __align__(16) float Ws[K * HDIM];
    __shared__ __align__(16) float Xs[8 * K];
    __shared__ float bnsc[K], bnsh[K];
    const int tid = threadIdx.x;
    const int row0 = blockIdx.x * 8;

    if (APPLY_BN) {
        if (tid < K) {
            float mean = stats[tid] * invN;
            float var = stats[K + tid] * invN - mean * mean;
            float sc = gamma[tid] * rsqrtf(var + BN_EPS);
            bnsc[tid] = sc;
            bnsh[tid] = beta[tid] - mean * sc;
        }
        __syncthreads();
    }
    for (int i = tid * 4; i < K * HDIM; i += 1024) {
        *(float4*)&Ws[i] = *(const float4*)&W[i];
    }
    for (int i = tid * 4; i < 8 * K; i += 1024) {
        int r = i / K, k = i % K;
        int gr = row0 + r;
        float4 v = make_float4(0.f, 0.f, 0.f, 0.f);
        if (gr < n) v = *(const float4*)&X[(size_t)gr * K + k];
        if (APPLY_BN) {
            v.x = fmaxf(v.x * bnsc[k]     + bnsh[k],     0.f);
            v.y = fmaxf(v.y * bnsc[k + 1] + bnsh[k + 1], 0.f);
            v.z = fmaxf(v.z * bnsc[k + 2] + bnsh[k + 2], 0.f);
            v.w = fmaxf(v.w * bnsc[k + 3] + bnsh[k + 3], 0.f);
        }
        *(float4*)&Xs[i] = v;
    }
    __syncthreads();
    const int r = tid >> 5, c = tid & 31;
    const int grow = row0 + r;
    if (grow < n) {
        float acc = 0.f;
#pragma unroll
        for (int k = 0; k < K; ++k) acc += Xs[r * K + k] * Ws[k * HDIM + c];
        Y[(size_t)grow * HDIM + c] = __float2bfloat16(dinv[grow] * acc);
    }
}

// bf16 pair unpack via bit ops (no cvt)
__device__ __forceinline__ float blo(unsigned u) { return __uint_as_float(u << 16); }
__device__ __forceinline__ float bhi(unsigned u) { return __uint_as_float(u & 0xffff0000u); }

// ---------- gather-aggregate: 8 lanes (1 oct) per row, uint2/lane = full 64B row per oct.
// One wave instruction gathers 8 edges. agg[n] = dinv[n]*(hp[n]+sum hp[src])+b ; fused BN-stats.
__global__ __launch_bounds__(256) void k_aggregate(const uint2* __restrict__ hp8,
                                                   const float* __restrict__ dinv,
                                                   const int* __restrict__ offsets,
                                                   const int* __restrict__ srcs,
                                                   const float* __restrict__ bias,
                                                   float* __restrict__ agg,
                                                   float* __restrict__ stats, int N) {
    const int tid = threadIdx.x;
    const int lane = tid & 63;
    const int j8 = lane & 7;    // uint2 index within row -> features [4*j8, 4*j8+4)
    const int oct = lane >> 3;  // 0..7, each oct owns edges e ≡ oct (mod 8)
    const int wid = (blockIdx.x * 256 + tid) >> 6;
    const int nw = (gridDim.x * 256) >> 6;
    const float4 b4 = *(const float4*)&bias[4 * j8];
    float s0 = 0, s1 = 0, s2 = 0, s3 = 0;
    float q0 = 0, q1 = 0, q2 = 0, q3 = 0;

    for (int n = wid; n < N; n += nw) {
        int beg = offsets[n], end = offsets[n + 1];
        float a0 = 0, a1 = 0, a2 = 0, a3 = 0;
        if (oct == 0) {  // self-loop once
            uint2 u = hp8[(size_t)n * 8 + j8];
            a0 = blo(u.x); a1 = bhi(u.x); a2 = blo(u.y); a3 = bhi(u.y);
        }
        int e = beg + oct;
        for (; e + 56 < end; e += 64) {  // 8 rows in flight per oct = 64 per wave
            int rr[8];
            uint2 uu[8];
#pragma unroll
            for (int k = 0; k < 8; ++k) rr[k] = srcs[e + 8 * k];
#pragma unroll
            for (int k = 0; k < 8; ++k) uu[k] = hp8[(size_t)rr[k] * 8 + j8];
#pragma unroll
            for (int k = 0; k < 8; ++k) {
                a0 += blo(uu[k].x); a1 += bhi(uu[k].x);
                a2 += blo(uu[k].y); a3 += bhi(uu[k].y);
            }
        }
        for (; e < end; e += 8) {
            uint2 u = hp8[(size_t)srcs[e] * 8 + j8];
            a0 += blo(u.x); a1 += bhi(u.x); a2 += blo(u.y); a3 += bhi(u.y);
        }
        // combine octs (xor 8/16/32 preserves j8)
#pragma unroll
        for (int off = 8; off < 64; off <<= 1) {
            a0 += __shfl_xor(a0, off);
            a1 += __shfl_xor(a1, off);
            a2 += __shfl_xor(a2, off);
            a3 += __shfl_xor(a3, off);
        }
        float d = dinv[n];
        float o0 = d * a0 + b4.x, o1 = d * a1 + b4.y;
        float o2 = d * a2 + b4.z, o3 = d * a3 + b4.w;
        if (oct == 0) *(float4*)&agg[(size_t)n * HDIM + 4 * j8] = make_float4(o0, o1, o2, o3);
        s0 += o0; s1 += o1; s2 += o2; s3 += o3;          // 8 copies -> scale 1/8 at flush
        q0 += o0 * o0; q1 += o1 * o1; q2 += o2 * o2; q3 += o3 * o3;
    }

    __shared__ float lss[4][64][4], lsq[4][64][4];
    int w = tid >> 6;
    lss[w][lane][0] = s0; lss[w][lane][1] = s1; lss[w][lane][2] = s2; lss[w][lane][3] = s3;
    lsq[w][lane][0] = q0; lsq[w][lane][1] = q1; lsq[w][lane][2] = q2; lsq[w][lane][3] = q3;
    __syncthreads();
    if (tid < 32) {
        int jj = tid >> 2, k = tid & 3;  // feature = 4*jj + k = tid
        float a = 0, b = 0;
#pragma unroll
        for (int ww = 0; ww < 4; ++ww)
            for (int o = 0; o < 8; ++o) {
                a += lss[ww][o * 8 + jj][k];
                b += lsq[ww][o * 8 + jj][k];
            }
        atomicAdd(&stats[tid], 0.125f * a);
        atomicAdd(&stats[HDIM + tid], 0.125f * b);
    }
}

// ---------- final batchnorm apply (layer 2, no relu), float4 ----------
__global__ void k_bnapply(const float* __restrict__ a, const float* __restrict__ stats,
                          const float* __restrict__ gamma, const float* __restrict__ beta,
                          float* __restrict__ out, int n, float invN) {
    int i = (blockIdx.x * 256 + threadIdx.x) * 4;
    if (i < n * HDIM) {
        int j = i & 31;
        float4 v = *(const float4*)&a[i];
        float r[4];
        float* vp = &v.x;
#pragma unroll
        for (int k = 0; k < 4; ++k) {
            float mean = stats[j + k] * invN;
            float var = stats[HDIM + j + k] * invN - mean * mean;
            float g = gamma[j + k] * rsqrtf(var + BN_EPS);
            r[k] = (vp[k] - mean) * g + beta[j + k];
        }
        *(float4*)&out[i] = make_float4(r[0], r[1], r[2], r[3]);
    }
}

extern "C" void kernel_launch(void* const* d_in, const int* in_sizes, int n_in,
                              void* d_out, int out_size, void* d_ws, size_t ws_size,
                              hipStream_t stream) {
    const float* x   = (const float*)d_in[0];
    const int*   ei  = (const int*)d_in[1];
    const float* W1  = (const float*)d_in[2];
    const float* b1  = (const float*)d_in[3];
    const float* g1  = (const float*)d_in[4];
    const float* be1 = (const float*)d_in[5];
    const float* W2  = (const float*)d_in[6];
    const float* b2  = (const float*)d_in[7];
    const float* g2  = (const float*)d_in[8];
    const float* be2 = (const float*)d_in[9];

    const int N = in_sizes[0] / FDIM;
    const int E = in_sizes[1] / 2;
    const int* row = ei;      // source
    const int* col = ei + E;  // target
    const int B = (N + BK - 1) / BK;   // buckets (391 for N=100k, fits BMAX)

    char* p = (char*)d_ws;
    auto alloc = [&](size_t bytes) { char* r = p; p += (bytes + 255) & ~(size_t)255; return r; };
    float*          dinv    = (float*)alloc((size_t)N * 4);
    int*            bcounts = (int*)alloc((size_t)B * 4);
    int*            boff    = (int*)alloc((size_t)(B + 1) * 4);
    int*            bcur    = (int*)alloc((size_t)B * 4);
    int*            noff    = (int*)alloc((size_t)(N + 1) * 4);
    unsigned*       pairs   = (unsigned*)alloc((size_t)E * 4);
    int*            srcs    = (int*)alloc((size_t)E * 4);
    __hip_bfloat16* B1      = (__hip_bfloat16*)alloc((size_t)N * HDIM * 2);  // hp [N][32] bf16
    float*          B2      = (float*)alloc((size_t)N * HDIM * 4);           // agg (fp32)
    float*          stats   = (float*)alloc(512);  // layer1 [0,64), layer2 [64,128)

    const float invN = 1.0f / (float)N;
    const int EBH = (E + CHUNK_H - 1) / CHUNK_H;
    const int EBP = (E + CHUNK_P - 1) / CHUNK_P;

    (void)hipMemsetAsync(bcounts, 0, (size_t)B * 4, stream);
    (void)hipMemsetAsync(stats, 0, 512, stream);

    // bucketed edge partition + per-bucket counting sort -> exact CSR (shared by both layers)
    k_hist2<<<EBH, 256, 0, stream>>>(col, bcounts, E, B);
    k_bscan<<<1, 256, 0, stream>>>(bcounts, boff, bcur, noff, B, E, N);
    k_partition<<<EBP, 256, 0, stream>>>(row, col, bcur, pairs, E, B);
    k_sort<<<B, 1024, 0, stream>>>(pairs, boff, srcs, noff, dinv, N);

    // layer 1
    k_gemm<FDIM, false><<<(N + 7) / 8, 256, 0, stream>>>(x, W1, dinv, B1, N,
                                                         nullptr, nullptr, nullptr, 0.f);
    k_aggregate<<<2048, 256, 0, stream>>>((const uint2*)B1, dinv, noff, srcs, b1, B2, stats, N);

    // layer 2 (BN1+ReLU fused into gemm2's X load)
    k_gemm<HDIM, true><<<(N + 7) / 8, 256, 0, stream>>>(B2, W2, dinv, B1, N,
                                                        stats, g1, be1, invN);
    k_aggregate<<<2048, 256, 0, stream>>>((const uint2*)B1, dinv, noff, srcs, b2, B2,
                                          stats + 2 * HDIM, N);
    k_bnapply<<<(N * HDIM / 4 + 255) / 256, 256, 0, stream>>>(B2, stats + 2 * HDIM, g2, be2,
                                                              (float*)d_out, N, invN);
}

// Round 10
// 589.454 us; speedup vs baseline: 1.2599x; 1.0533x over previous
//
#include <hip/hip_runtime.h>
#include <hip/hip_bf16.h>

#define FDIM 128
#define HDIM 32
#define BN_EPS 1e-5f
#define BK 256         // destination nodes per bucket
#define NBITS 8        // log2(BK)
#define CHUNK_H 4096   // edges per hist block
#define CHUNK_P 4096   // edges per partition block (16KB LDS staging -> 7 blocks/CU)
#define BMAX 512       // max buckets (N <= 131072)

// ---------- per-bucket histogram (LDS) ----------
__global__ void k_hist2(const int* __restrict__ col, int* __restrict__ bcounts, int E, int B) {
    __shared__ int h[BMAX];
    for (int i = threadIdx.x; i < B; i += 256) h[i] = 0;
    __syncthreads();
    int base = blockIdx.x * CHUNK_H;
    int end = min(base + CHUNK_H, E);
    for (int e = base + threadIdx.x; e < end; e += 256)
        atomicAdd(&h[col[e] >> NBITS], 1);
    __syncthreads();
    for (int i = threadIdx.x; i < B; i += 256)
        if (h[i]) atomicAdd(&bcounts[i], h[i]);
}

// ---------- single-block exclusive scan of bucket counts ----------
__global__ void k_bscan(const int* __restrict__ bcounts, int* __restrict__ boff,
                        int* __restrict__ bcur, int* __restrict__ noff, int B, int E, int N) {
    __shared__ int tsum[256];
    __shared__ int wtot[4];
    const int t = threadIdx.x;
    const int per = (B + 255) / 256;
    const int b0 = t * per;
    int s = 0;
    for (int k = 0; k < per; ++k) { int i = b0 + k; if (i < B) s += bcounts[i]; }
    tsum[t] = s;
    __syncthreads();
    int lane = t & 63, w = t >> 6;
    int v = tsum[t];
    int inc = v;
    for (int off = 1; off < 64; off <<= 1) {
        int u = __shfl_up(inc, off);
        if (lane >= off) inc += u;
    }
    if (lane == 63) wtot[w] = inc;
    __syncthreads();
    int pre = 0;
    for (int k = 0; k < w; ++k) pre += wtot[k];
    int acc = pre + inc - v;  // exclusive prefix
    for (int k = 0; k < per; ++k) {
        int i = b0 + k;
        if (i < B) { boff[i] = acc; bcur[i] = acc; acc += bcounts[i]; }
    }
    if (t == 0) { boff[B] = E; noff[N] = E; }
}

// ---------- partition with LDS staging: pairs[] grouped by dst bucket, coalesced writes ----------
__global__ __launch_bounds__(256) void k_partition(const int* __restrict__ row,
                                                   const int* __restrict__ col,
                                                   int* __restrict__ bcur,
                                                   unsigned* __restrict__ pairs,
                                                   int E, int B) {
    __shared__ int h[BMAX];          // counts -> local cursors
    __shared__ int lbase[BMAX + 1];  // local exclusive scan
    __shared__ int delta[BMAX];      // global_base - local_base
    __shared__ unsigned pk[CHUNK_P]; // bucket-sorted packed pairs
    const int t = threadIdx.x;
    const int base = blockIdx.x * CHUNK_P;
    const int end = min(base + CHUNK_P, E);

    for (int i = t; i < B; i += 256) h[i] = 0;
    __syncthreads();
    for (int e = base + t; e < end; e += 256)
        atomicAdd(&h[col[e] >> NBITS], 1);
    __syncthreads();
    if (t < 64) {
        int carry = 0;
        for (int bb = 0; bb < B; bb += 64) {
            int idx = bb + t;
            int v = (idx < B) ? h[idx] : 0;
            int inc = v;
            for (int off = 1; off < 64; off <<= 1) {
                int u = __shfl_up(inc, off);
                if (t >= off) inc += u;
            }
            if (idx < B) lbase[idx] = carry + inc - v;
            carry += __shfl(inc, 63);
        }
        if (t == 0) lbase[B] = carry;
    }
    __syncthreads();
    for (int b = t; b < B; b += 256) {
        int c = h[b];
        if (c) {
            int g = atomicAdd(&bcur[b], c);
            delta[b] = g - lbase[b];
        }
    }
    __syncthreads();
    for (int b = t; b < B; b += 256) h[b] = lbase[b];
    __syncthreads();
    for (int e = base + t; e < end; e += 256) {
        int c = col[e], r = row[e];
        int lpos = atomicAdd(&h[c >> NBITS], 1);
        pk[lpos] = ((unsigned)r << NBITS) | (unsigned)(c & (BK - 1));
    }
    __syncthreads();
    const int tot = lbase[B];
    for (int i = t; i < tot; i += 256) {
        int lo = 0, hi = B - 1;
        while (lo < hi) {
            int mid = (lo + hi + 1) >> 1;
            if (lbase[mid] <= i) lo = mid; else hi = mid - 1;
        }
        pairs[delta[lo] + i] = pk[i];
    }
}

// ---------- per-bucket counting sort -> exact CSR (srcs, noff) + dinv ----------
__global__ __launch_bounds__(1024) void k_sort(const unsigned* __restrict__ pairs,
                                               const int* __restrict__ boff,
                                               int* __restrict__ srcs, int* __restrict__ noff,
                                               float* __restrict__ dinv, int N) {
    __shared__ int cnt[BK];
    __shared__ int cur[BK];
    const int bb = blockIdx.x;
    const int t = threadIdx.x;
    if (t < BK) cnt[t] = 0;
    __syncthreads();
    const int beg = boff[bb], end = boff[bb + 1];
    for (int i = beg + t; i < end; i += 1024)
        atomicAdd(&cnt[pairs[i] & (BK - 1)], 1);
    __syncthreads();
    if (t < 64) {
        int carry = 0;
        for (int base = 0; base < BK; base += 64) {
            int v = cnt[base + t];
            int inc = v;
            for (int off = 1; off < 64; off <<= 1) {
                int u = __shfl_up(inc, off);
                if (t >= off) inc += u;
            }
            cur[base + t] = beg + carry + inc - v;
            carry += __shfl(inc, 63);
        }
    }
    __syncthreads();
    if (t < BK) {
        int n = bb * BK + t;
        if (n < N) {
            noff[n] = cur[t];
            dinv[n] = rsqrtf((float)(cnt[t] + 1));  // +1 self-loop
        }
    }
    __syncthreads();
    for (int i = beg + t; i < end; i += 1024) {
        unsigned p = pairs[i];
        int pos = atomicAdd(&cur[p & (BK - 1)], 1);
        srcs[pos] = (int)(p >> NBITS);
    }
}

// ---------- GEMM: Y[n,32] = bf16(dinv[n]*(X[n,K]@W[K,32])); optional fused BN+ReLU on X ----------
template <int K, bool APPLY_BN>
__global__ void k_gemm(const float* __restrict__ X, const float* __restrict__ W,
                       const float* __restrict__ dinv, __hip_bfloat16* __restrict__ Y, int n,
                       const float* __restrict__ stats, const float* __restrict__ gamma,
                       const float* __restrict__ beta, float invN) {
    __shared__ __align__(16) float Ws[K * HDIM];
    __shared__ __align__(16) float Xs[8 * K];
    __shared__ float bnsc[K], bnsh[K];
    const int tid = threadIdx.x;
    const int row0 = blockIdx.x * 8;

    if (APPLY_BN) {
        if (tid < K) {
            float mean = stats[tid] * invN;
            float var = stats[K + tid] * invN - mean * mean;
            float sc = gamma[tid] * rsqrtf(var + BN_EPS);
            bnsc[tid] = sc;
            bnsh[tid] = beta[tid] - mean * sc;
        }
        __syncthreads();
    }
    for (int i = tid * 4; i < K * HDIM; i += 1024) {
        *(float4*)&Ws[i] = *(const float4*)&W[i];
    }
    for (int i = tid * 4; i < 8 * K; i += 1024) {
        int r = i / K, k = i % K;
        int gr = row0 + r;
        float4 v = make_float4(0.f, 0.f, 0.f, 0.f);
        if (gr < n) v = *(const float4*)&X[(size_t)gr * K + k];
        if (APPLY_BN) {
            v.x = fmaxf(v.x * bnsc[k]     + bnsh[k],     0.f);
            v.y = fmaxf(v.y * bnsc[k + 1] + bnsh[k + 1], 0.f);
            v.z = fmaxf(v.z * bnsc[k + 2] + bnsh[k + 2], 0.f);
            v.w = fmaxf(v.w * bnsc[k + 3] + bnsh[k + 3], 0.f);
        }
        *(float4*)&Xs[i] = v;
    }
    __syncthreads();
    const int r = tid >> 5, c = tid & 31;
    const int grow = row0 + r;
    if (grow < n) {
        float acc = 0.f;
#pragma unroll
        for (int k = 0; k < K; ++k) acc += Xs[r * K + k] * Ws[k * HDIM + c];
        Y[(size_t)grow * HDIM + c] = __float2bfloat16(dinv[grow] * acc);
    }
}

// bf16 pair unpack via bit ops (no cvt)
__device__ __forceinline__ float blo(unsigned u) { return __uint_as_float(u << 16); }
__device__ __forceinline__ float bhi(unsigned u) { return __uint_as_float(u & 0xffff0000u); }

// ---------- gather-aggregate: 8 lanes (1 oct) per row, uint2/lane = full 64B row per oct.
// Progressive MLP ladder (8/4/2/1 loads in flight) so nearly all edges are pipelined.
__global__ __launch_bounds__(256) void k_aggregate(const uint2* __restrict__ hp8,
                                                   const float* __restrict__ dinv,
                                                   const int* __restrict__ offsets,
                                                   const int* __restrict__ srcs,
                                                   const float* __restrict__ bias,
                                                   float* __restrict__ agg,
                                                   float* __restrict__ stats, int N) {
    const int tid = threadIdx.x;
    const int lane = tid & 63;
    const int j8 = lane & 7;    // uint2 index within row -> features [4*j8, 4*j8+4)
    const int oct = lane >> 3;  // 0..7, oct o owns edges e ≡ o (mod 8)
    const int wid = (blockIdx.x * 256 + tid) >> 6;
    const int nw = (gridDim.x * 256) >> 6;
    const float4 b4 = *(const float4*)&bias[4 * j8];
    float s0 = 0, s1 = 0, s2 = 0, s3 = 0;
    float q0 = 0, q1 = 0, q2 = 0, q3 = 0;

    for (int n = wid; n < N; n += nw) {
        int beg = offsets[n], end = offsets[n + 1];
        float a0 = 0, a1 = 0, a2 = 0, a3 = 0;
        if (oct == 0) {  // self-loop once
            uint2 u = hp8[(size_t)n * 8 + j8];
            a0 = blo(u.x); a1 = bhi(u.x); a2 = blo(u.y); a3 = bhi(u.y);
        }
        int e = beg + oct;
        // rung 1: 8 loads in flight, 64 edges/wave-iter
        for (; e + 56 < end; e += 64) {
            int rr[8]; uint2 uu[8];
#pragma unroll
            for (int k = 0; k < 8; ++k) rr[k] = srcs[e + 8 * k];
#pragma unroll
            for (int k = 0; k < 8; ++k) uu[k] = hp8[(size_t)rr[k] * 8 + j8];
#pragma unroll
            for (int k = 0; k < 8; ++k) {
                a0 += blo(uu[k].x); a1 += bhi(uu[k].x);
                a2 += blo(uu[k].y); a3 += bhi(uu[k].y);
            }
        }
        // rung 2: 4 loads, 32 edges
        if (e + 24 < end) {
            int rr[4]; uint2 uu[4];
#pragma unroll
            for (int k = 0; k < 4; ++k) rr[k] = srcs[e + 8 * k];
#pragma unroll
            for (int k = 0; k < 4; ++k) uu[k] = hp8[(size_t)rr[k] * 8 + j8];
#pragma unroll
            for (int k = 0; k < 4; ++k) {
                a0 += blo(uu[k].x); a1 += bhi(uu[k].x);
                a2 += blo(uu[k].y); a3 += bhi(uu[k].y);
            }
            e += 32;
        }
        // rung 3: 2 loads, 16 edges
        if (e + 8 < end) {
            int r0 = srcs[e], r1 = srcs[e + 8];
            uint2 u0 = hp8[(size_t)r0 * 8 + j8];
            uint2 u1 = hp8[(size_t)r1 * 8 + j8];
            a0 += blo(u0.x) + blo(u1.x); a1 += bhi(u0.x) + bhi(u1.x);
            a2 += blo(u0.y) + blo(u1.y); a3 += bhi(u0.y) + bhi(u1.y);
            e += 16;
        }
        // rung 4: singles (at most 1 per oct)
        for (; e < end; e += 8) {
            uint2 u = hp8[(size_t)srcs[e] * 8 + j8];
            a0 += blo(u.x); a1 += bhi(u.x); a2 += blo(u.y); a3 += bhi(u.y);
        }
        // combine octs (xor 8/16/32 preserves j8)
#pragma unroll
        for (int off = 8; off < 64; off <<= 1) {
            a0 += __shfl_xor(a0, off);
            a1 += __shfl_xor(a1, off);
            a2 += __shfl_xor(a2, off);
            a3 += __shfl_xor(a3, off);
        }
        float d = dinv[n];
        float o0 = d * a0 + b4.x, o1 = d * a1 + b4.y;
        float o2 = d * a2 + b4.z, o3 = d * a3 + b4.w;
        if (oct == 0) *(float4*)&agg[(size_t)n * HDIM + 4 * j8] = make_float4(o0, o1, o2, o3);
        s0 += o0; s1 += o1; s2 += o2; s3 += o3;          // 8 copies -> scale 1/8 at flush
        q0 += o0 * o0; q1 += o1 * o1; q2 += o2 * o2; q3 += o3 * o3;
    }

    __shared__ float lss[4][64][4], lsq[4][64][4];
    int w = tid >> 6;
    lss[w][lane][0] = s0; lss[w][lane][1] = s1; lss[w][lane][2] = s2; lss[w][lane][3] = s3;
    lsq[w][lane][0] = q0; lsq[w][lane][1] = q1; lsq[w][lane][2] = q2; lsq[w][lane][3] = q3;
    __syncthreads();
    if (tid < 32) {
        int jj = tid >> 2, k = tid & 3;  // feature = tid
        float a = 0, b = 0;
#pragma unroll
        for (int ww = 0; ww < 4; ++ww)
            for (int o = 0; o < 8; ++o) {
                a += lss[ww][o * 8 + jj][k];
                b += lsq[ww][o * 8 + jj][k];
            }
        atomicAdd(&stats[tid], 0.125f * a);
        atomicAdd(&stats[HDIM + tid], 0.125f * b);
    }
}

// ---------- final batchnorm apply (layer 2, no relu), float4 ----------
__global__ void k_bnapply(const float* __restrict__ a, const float* __restrict__ stats,
                          const float* __restrict__ gamma, const float* __restrict__ beta,
                          float* __restrict__ out, int n, float invN) {
    int i = (blockIdx.x * 256 + threadIdx.x) * 4;
    if (i < n * HDIM) {
        int j = i & 31;
        float4 v = *(const float4*)&a[i];
        float r[4];
        float* vp = &v.x;
#pragma unroll
        for (int k = 0; k < 4; ++k) {
            float mean = stats[j + k] * invN;
            float var = stats[HDIM + j + k] * invN - mean * mean;
            float g = gamma[j + k] * rsqrtf(var + BN_EPS);
            r[k] = (vp[k] - mean) * g + beta[j + k];
        }
        *(float4*)&out[i] = make_float4(r[0], r[1], r[2], r[3]);
    }
}

extern "C" void kernel_launch(void* const* d_in, const int* in_sizes, int n_in,
                              void* d_out, int out_size, void* d_ws, size_t ws_size,
                              hipStream_t stream) {
    const float* x   = (const float*)d_in[0];
    const int*   ei  = (const int*)d_in[1];
    const float* W1  = (const float*)d_in[2];
    const float* b1  = (const float*)d_in[3];
    const float* g1  = (const float*)d_in[4];
    const float* be1 = (const float*)d_in[5];
    const float* W2  = (const float*)d_in[6];
    const float* b2  = (const float*)d_in[7];
    const float* g2  = (const float*)d_in[8];
    const float* be2 = (const float*)d_in[9];

    const int N = in_sizes[0] / FDIM;
    const int E = in_sizes[1] / 2;
    const int* row = ei;      // source
    const int* col = ei + E;  // target
    const int B = (N + BK - 1) / BK;   // buckets (391 for N=100k, fits BMAX)

    char* p = (char*)d_ws;
    auto alloc = [&](size_t bytes) { char* r = p; p += (bytes + 255) & ~(size_t)255; return r; };
    float*          dinv    = (float*)alloc((size_t)N * 4);
    int*            bcounts = (int*)alloc((size_t)B * 4);
    int*            boff    = (int*)alloc((size_t)(B + 1) * 4);
    int*            bcur    = (int*)alloc((size_t)B * 4);
    int*            noff    = (int*)alloc((size_t)(N + 1) * 4);
    unsigned*       pairs   = (unsigned*)alloc((size_t)E * 4);
    int*            srcs    = (int*)alloc((size_t)E * 4);
    __hip_bfloat16* B1      = (__hip_bfloat16*)alloc((size_t)N * HDIM * 2);  // hp [N][32] bf16
    float*          B2      = (float*)alloc((size_t)N * HDIM * 4);           // agg (fp32)
    float*          stats   = (float*)alloc(512);  // layer1 [0,64), layer2 [64,128)

    const float invN = 1.0f / (float)N;
    const int EBH = (E + CHUNK_H - 1) / CHUNK_H;
    const int EBP = (E + CHUNK_P - 1) / CHUNK_P;

    (void)hipMemsetAsync(bcounts, 0, (size_t)B * 4, stream);
    (void)hipMemsetAsync(stats, 0, 512, stream);

    // bucketed edge partition + per-bucket counting sort -> exact CSR (shared by both layers)
    k_hist2<<<EBH, 256, 0, stream>>>(col, bcounts, E, B);
    k_bscan<<<1, 256, 0, stream>>>(bcounts, boff, bcur, noff, B, E, N);
    k_partition<<<EBP, 256, 0, stream>>>(row, col, bcur, pairs, E, B);
    k_sort<<<B, 1024, 0, stream>>>(pairs, boff, srcs, noff, dinv, N);

    // layer 1
    k_gemm<FDIM, false><<<(N + 7) / 8, 256, 0, stream>>>(x, W1, dinv, B1, N,
                                                         nullptr, nullptr, nullptr, 0.f);
    k_aggregate<<<2048, 256, 0, stream>>>((const uint2*)B1, dinv, noff, srcs, b1, B2, stats, N);

    // layer 2 (BN1+ReLU fused into gemm2's X load)
    k_gemm<HDIM, true><<<(N + 7) / 8, 256, 0, stream>>>(B2, W2, dinv, B1, N,
                                                        stats, g1, be1, invN);
    k_aggregate<<<2048, 256, 0, stream>>>((const uint2*)B1, dinv, noff, srcs, b2, B2,
                                          stats + 2 * HDIM, N);
    k_bnapply<<<(N * HDIM / 4 + 255) / 256, 256, 0, stream>>>(B2, stats + 2 * HDIM, g2, be2,
                                                              (float*)d_out, N, invN);
}